// Round 10
// baseline (70.474 us; speedup 1.0000x reference)
//
#include <hip/hip_runtime.h>
#include <math.h>

// TaskAdaptiveRouter via split-bf16 4-pass MFMA (R8 engine) + K-split x2 + depth-6
// x prefetch (R9 schedule). logits = x @ Wr[:, :2048]^T + task_logits; softmax;
// top2; aux. 4 passes (hh,hl,lh,ll) keep logit error ~2e-7 (index-exact top2).
//
// d_out (f32): [0,32768) topw ; [32768,65536) topi(float) ; [65536,1114112) probs ;
//              [1114112] aux.
// d_ws: [0,256) tl[4][64] ; [256,1280) P/F slots ; [1280..) W B-frags wh,wl
//       (65536 u32 each). B-frag: dword ((s*4+g)*64+lane)*4+d ; s=k>>5 in [0,64).

#define DDIM 2048
#define WROW 2064

typedef unsigned int u32;
typedef unsigned short u16;
using short8 = __attribute__((ext_vector_type(8))) short;
using f32x4  = __attribute__((ext_vector_type(4))) float;

__device__ __forceinline__ u16 bf16rne(float f) {
    u32 u = __float_as_uint(f);
    return (u16)((u + 0x7FFFu + ((u >> 16) & 1u)) >> 16);
}

// ---------------- kernel 0: build W B-fragments (hi/lo bf16) ----------------------
__global__ void k0_wsplit(const float* __restrict__ Wr, u32* __restrict__ wh,
                          u32* __restrict__ wl) {
    const int g = blockIdx.x * 256 + threadIdx.x;    // 0..65535
    const int e  = g >> 10;                          // expert 0..63
    const int kp = g & 1023;                         // k-pair 0..1023
    const int k  = kp * 2;
    const int step = k >> 5, kb = (k >> 3) & 3, d = (k >> 1) & 3;
    const int grp = e >> 4, lane = kb * 16 + (e & 15);
    const float w0 = Wr[(size_t)e * WROW + k];
    const float w1 = Wr[(size_t)e * WROW + k + 1];
    const u16 h0 = bf16rne(w0);
    const u16 h1 = bf16rne(w1);
    const u16 l0 = bf16rne(w0 - __uint_as_float((u32)h0 << 16));
    const u16 l1 = bf16rne(w1 - __uint_as_float((u32)h1 << 16));
    const u32 oi = (u32)(((step * 4 + grp) * 64 + lane) * 4 + d);
    wh[oi] = ((u32)h1 << 16) | h0;
    wl[oi] = ((u32)l1 << 16) | l0;
}

// ---------------- kernel 1: task proj + task logits + zero P/F slots -------------
__global__ void k1_task(const float* __restrict__ z, const float* __restrict__ Wp,
                        const float* __restrict__ bp, const float* __restrict__ Wr,
                        const float* __restrict__ eb, float* __restrict__ wsb) {
    __shared__ float tp[4][16];
    const int t = threadIdx.x;
    if (t < 64) {
        const int b = t >> 4, r = t & 15;
        float s = bp[r];
        #pragma unroll
        for (int i = 0; i < 16; ++i) s += z[b * 16 + i] * Wp[r * 16 + i];
        tp[b][r] = 0.5f * s * (1.0f + erff(s * 0.70710678118654752440f));
    }
    #pragma unroll
    for (int i = t; i < 1024; i += 256) wsb[256 + i] = 0.0f;   // zero 8 P/F slots
    __syncthreads();
    {
        const int b = t >> 6, e = t & 63;
        const float* wr = Wr + (size_t)e * WROW + DDIM;
        float s = eb[e];
        #pragma unroll
        for (int i = 0; i < 16; ++i) s += tp[b][i] * wr[i];
        wsb[b * 64 + e] = s;
    }
}

// ---------------- kernel 2: MFMA logits + softmax + top2 + probs + P/f -----------
// 512 thr = 8 waves: wave (tg = wv&3, h = wv>>2): tokens tg*16..+15, K-half h.
__global__ __launch_bounds__(512, 2) void k2_mfma(const float* __restrict__ x,
                                                  const float* __restrict__ wsb,
                                                  const short8* __restrict__ bfh,
                                                  const short8* __restrict__ bfl,
                                                  float* __restrict__ wacc,
                                                  float* __restrict__ out) {
    __shared__ float lg[2][64 * 68];   // per-K-half logit partials (34.8 KB)
    __shared__ float pf[8 * 128];      // P/f partials (4 KB)

    const int tid   = threadIdx.x;
    const int wv    = tid >> 6;       // 0..7
    const int tg    = wv & 3;         // token group
    const int h     = wv >> 2;        // K-half
    const int lane  = tid & 63;
    const int row   = lane & 15;      // A row (token within 16-tile)
    const int kg    = lane >> 4;      // k-group 0..3
    const int tok0b = blockIdx.x * 64;
    const int tok0  = tok0b + tg * 16;
    const int bb    = tok0b >> 12;    // batch (uniform per block)

    const float* xp = x + (size_t)(tok0 + row) * DDIM + h * 1024 + kg * 8;

    f32x4 acc[4];
    #pragma unroll
    for (int g = 0; g < 4; ++g) {
        const float tl = (h == 0) ? wsb[bb * 64 + g * 16 + row] : 0.0f;
        acc[g] = (f32x4){tl, tl, tl, tl};
    }

#define LOADB(s, BH, BL) do {                                                   \
        _Pragma("unroll")                                                       \
        for (int g = 0; g < 4; ++g) {                                           \
            BH[g] = bfh[((s) * 4 + g) * 64 + lane];                             \
            BL[g] = bfl[((s) * 4 + g) * 64 + lane];                             \
        }                                                                       \
    } while (0)

#define MSTEP(xa, xb, BH, BL) do {                                              \
        const float vv[8] = {xa.x, xa.y, xa.z, xa.w, xb.x, xb.y, xb.z, xb.w};   \
        short8 Ah, Al;                                                          \
        _Pragma("unroll")                                                       \
        for (int j = 0; j < 8; ++j) {                                           \
            const float v = vv[j];                                              \
            const u16 hh = bf16rne(v);                                          \
            const u16 ll = bf16rne(v - __uint_as_float((u32)hh << 16));         \
            Ah[j] = (short)hh; Al[j] = (short)ll;                               \
        }                                                                       \
        _Pragma("unroll")                                                       \
        for (int g = 0; g < 4; ++g) {                                           \
            acc[g] = __builtin_amdgcn_mfma_f32_16x16x32_bf16(Ah, BH[g], acc[g], 0, 0, 0); \
            acc[g] = __builtin_amdgcn_mfma_f32_16x16x32_bf16(Ah, BL[g], acc[g], 0, 0, 0); \
            acc[g] = __builtin_amdgcn_mfma_f32_16x16x32_bf16(Al, BH[g], acc[g], 0, 0, 0); \
            acc[g] = __builtin_amdgcn_mfma_f32_16x16x32_bf16(Al, BL[g], acc[g], 0, 0, 0); \
        }                                                                       \
    } while (0)

    // x prefetch ring, depth 6 (all indices static after full unroll);
    // B double-buffer, depth 2 (L2-resident); s-index masked &63 (in-bounds).
    float4 xa[6], xb[6];
    #pragma unroll
    for (int p = 0; p < 6; ++p) {
        xa[p] = *(const float4*)(xp + p * 32);
        xb[p] = *(const float4*)(xp + p * 32 + 4);
    }
    short8 bh0[4], bl0[4], bh1[4], bl1[4];
    const int s0 = h * 32;
    LOADB(s0, bh0, bl0);

    #pragma unroll
    for (int t = 0; t < 32; t += 2) {
        {   // even step: consume x[t], B(t); prefetch x[t+6], B(t+1)
            const int ps = (t + 6) & 31;
            const float4 na = *(const float4*)(xp + ps * 32);
            const float4 nb = *(const float4*)(xp + ps * 32 + 4);
            LOADB((s0 + t + 1) & 63, bh1, bl1);
            MSTEP(xa[t % 6], xb[t % 6], bh0, bl0);
            xa[t % 6] = na; xb[t % 6] = nb;
        }
        {   // odd step: consume x[t+1], B(t+1); prefetch x[t+7], B(t+2)
            const int ps = (t + 7) & 31;
            const float4 na = *(const float4*)(xp + ps * 32);
            const float4 nb = *(const float4*)(xp + ps * 32 + 4);
            LOADB((s0 + t + 2) & 63, bh0, bl0);
            MSTEP(xa[(t + 1) % 6], xb[(t + 1) % 6], bh1, bl1);
            xa[(t + 1) % 6] = na; xb[(t + 1) % 6] = nb;
        }
    }
#undef LOADB
#undef MSTEP

    // ---- partial-logit exchange: C layout col(lane&15)=expert, row=kg*4+r=token ----
    #pragma unroll
    for (int g = 0; g < 4; ++g)
        #pragma unroll
        for (int r = 0; r < 4; ++r)
            lg[h][(tg * 16 + kg * 4 + r) * 68 + g * 16 + row] = acc[g][r];
    __syncthreads();

    // ---- softmax/top2 for tokens wv*8 .. wv*8+7 ; lane = expert ----
    {
        float pacc = 0.0f, facc = 0.0f;
        for (int i = 0; i < 8; ++i) {
            const int tk = wv * 8 + i;
            const float v = lg[0][tk * 68 + lane] + lg[1][tk * 68 + lane];
            float m1 = v; int i1 = lane;
            #pragma unroll
            for (int off = 32; off; off >>= 1) {
                const float ov = __shfl_xor(m1, off, 64);
                const int   oi = __shfl_xor(i1, off, 64);
                if (ov > m1 || (ov == m1 && oi < i1)) { m1 = ov; i1 = oi; }
            }
            const float vx = (lane == i1) ? -3.4e38f : v;
            float m2 = vx; int i2 = lane;
            #pragma unroll
            for (int off = 32; off; off >>= 1) {
                const float ov = __shfl_xor(m2, off, 64);
                const int   oi = __shfl_xor(i2, off, 64);
                if (ov > m2 || (ov == m2 && oi < i2)) { m2 = ov; i2 = oi; }
            }
            const float p = __expf(v - m1);
            float s = p;
            #pragma unroll
            for (int off = 32; off; off >>= 1) s += __shfl_xor(s, off, 64);
            const float rZ = 1.0f / s;
            const float pn = p * rZ;
            const int   T  = tok0b + tk;
            out[65536 + (size_t)T * 64 + lane] = pn;      // coalesced 256 B
            pacc += pn;
            facc += (lane == i1 ? 1.0f : 0.0f) + (lane == i2 ? 1.0f : 0.0f);
            if (lane == 0) {
                const float q1 = rZ, q2 = __expf(m2 - m1) * rZ;
                const float dn = 1.0f / (q1 + q2 + 1e-8f);
                float2 tw; tw.x = q1 * dn; tw.y = q2 * dn;
                *(float2*)(out + (size_t)T * 2) = tw;
                float2 ti; ti.x = (float)i1; ti.y = (float)i2;
                *(float2*)(out + 32768 + (size_t)T * 2) = ti;
            }
        }
        pf[wv * 128 + lane]      = pacc;
        pf[wv * 128 + 64 + lane] = facc;
    }
    __syncthreads();

    // ---- block-level P/f reduce -> one atomic per address per block (8 slots) ----
    if (wv == 0) {
        float ps = 0.0f, fs = 0.0f;
        #pragma unroll
        for (int w2 = 0; w2 < 8; ++w2) {
            ps += pf[w2 * 128 + lane];
            fs += pf[w2 * 128 + 64 + lane];
        }
        const int slot = blockIdx.x & 7;
        atomicAdd(wacc + slot * 128 + lane, ps);
        atomicAdd(wacc + slot * 128 + 64 + lane, fs);
    }
}

// ---------------- kernel 3: aux loss ----------------------------------------------
__global__ void k3_aux(const float* __restrict__ wsb, float* __restrict__ out) {
    const int e = threadIdx.x;  // 64 threads
    float P = 0.0f, F = 0.0f;
    #pragma unroll
    for (int s = 0; s < 8; ++s) {
        P += wsb[256 + s * 128 + e];
        F += wsb[256 + s * 128 + 64 + e];
    }
    float val = P * F;
    #pragma unroll
    for (int off = 32; off; off >>= 1) val += __shfl_xor(val, off, 64);
    if (e == 0)
        out[1114112] = 64.0f * val / (16384.0f * 2.0f * 16384.0f);
}

extern "C" void kernel_launch(void* const* d_in, const int* in_sizes, int n_in,
                              void* d_out, int out_size, void* d_ws, size_t ws_size,
                              hipStream_t stream) {
    (void)in_sizes; (void)n_in; (void)out_size; (void)ws_size;
    const float* x  = (const float*)d_in[0];
    const float* z  = (const float*)d_in[1];
    const float* Wr = (const float*)d_in[2];
    const float* Wp = (const float*)d_in[3];
    const float* bp = (const float*)d_in[4];
    const float* eb = (const float*)d_in[5];
    float* out = (float*)d_out;
    float* wsb = (float*)d_ws;
    u32*   wfH = (u32*)(wsb + 1280);          // 65536 u32 (256 KB)
    u32*   wfL = wfH + 65536;                 // 65536 u32 (256 KB)

    hipLaunchKernelGGL(k0_wsplit, dim3(256), dim3(256), 0, stream, Wr, wfH, wfL);
    hipLaunchKernelGGL(k1_task,   dim3(1),   dim3(256), 0, stream, z, Wp, bp, Wr, eb, wsb);
    hipLaunchKernelGGL(k2_mfma,   dim3(256), dim3(512), 0, stream, x, wsb,
                       (const short8*)wfH, (const short8*)wfL, wsb + 256, out);
    hipLaunchKernelGGL(k3_aux,    dim3(1),   dim3(64),  0, stream, wsb, out);
}

// Round 11
// 55.900 us; speedup vs baseline: 1.2607x; 1.2607x over previous
//
#include <hip/hip_runtime.h>
#include <math.h>

// TaskAdaptiveRouter via split-bf16 4-pass MFMA.
// R10: separate latency classes by QUEUE: B-frags (shared, L2) -> LDS via producer
// wave DMA (vmcnt = DMA only); x (private, HBM) -> per-consumer asm load ring,
// vmcnt = x only, static vmcnt(10); B reads via ds_read (lgkm, self-draining via
// MFMA data deps). R8/R9 mixed x+B in one vmcnt queue -> every B wait drained the
// freshest x load (in-order counter) -> ~900cy stall per step.
//
// d_out (f32): [0,32768) topw ; [32768,65536) topi(float) ; [65536,1114112) probs ;
//              [1114112] aux.
// d_ws: [0,256) tl[4][64] ; [256,1280) P/F slots ; [1280..) W B-frags wh,wl
//       (65536 u32 each). B-frag: dword ((s*4+g)*64+lane)*4+d ; s=k>>5 in [0,64).

#define DDIM 2048
#define WROW 2064

typedef unsigned int u32;
typedef unsigned short u16;
typedef unsigned long long u64;
using short8 = __attribute__((ext_vector_type(8))) short;
using f32x4  = __attribute__((ext_vector_type(4))) float;

typedef const __attribute__((address_space(1))) u32* gp1;
typedef __attribute__((address_space(3))) u32* lp3;

#define BAR() do {                                                              \
        __builtin_amdgcn_s_barrier();                                           \
        asm volatile("" ::: "memory");                                          \
        __builtin_amdgcn_sched_barrier(0);                                      \
    } while (0)

__device__ __forceinline__ u16 bf16rne(float f) {
    u32 u = __float_as_uint(f);
    return (u16)((u + 0x7FFFu + ((u >> 16) & 1u)) >> 16);
}

// ---------------- kernel 0: build W B-fragments (hi/lo bf16) ----------------------
__global__ void k0_wsplit(const float* __restrict__ Wr, u32* __restrict__ wh,
                          u32* __restrict__ wl) {
    const int g = blockIdx.x * 256 + threadIdx.x;    // 0..65535
    const int e  = g >> 10;                          // expert 0..63
    const int kp = g & 1023;                         // k-pair 0..1023
    const int k  = kp * 2;
    const int step = k >> 5, kb = (k >> 3) & 3, d = (k >> 1) & 3;
    const int grp = e >> 4, lane = kb * 16 + (e & 15);
    const float w0 = Wr[(size_t)e * WROW + k];
    const float w1 = Wr[(size_t)e * WROW + k + 1];
    const u16 h0 = bf16rne(w0);
    const u16 h1 = bf16rne(w1);
    const u16 l0 = bf16rne(w0 - __uint_as_float((u32)h0 << 16));
    const u16 l1 = bf16rne(w1 - __uint_as_float((u32)h1 << 16));
    const u32 oi = (u32)(((step * 4 + grp) * 64 + lane) * 4 + d);
    wh[oi] = ((u32)h1 << 16) | h0;
    wl[oi] = ((u32)l1 << 16) | l0;
}

// ---------------- kernel 1: task proj + task logits + zero P/F slots -------------
__global__ void k1_task(const float* __restrict__ z, const float* __restrict__ Wp,
                        const float* __restrict__ bp, const float* __restrict__ Wr,
                        const float* __restrict__ eb, float* __restrict__ wsb) {
    __shared__ float tp[4][16];
    const int t = threadIdx.x;
    if (t < 64) {
        const int b = t >> 4, r = t & 15;
        float s = bp[r];
        #pragma unroll
        for (int i = 0; i < 16; ++i) s += z[b * 16 + i] * Wp[r * 16 + i];
        tp[b][r] = 0.5f * s * (1.0f + erff(s * 0.70710678118654752440f));
    }
    #pragma unroll
    for (int i = t; i < 1024; i += 256) wsb[256 + i] = 0.0f;   // zero 8 P/F slots
    __syncthreads();
    {
        const int b = t >> 6, e = t & 63;
        const float* wr = Wr + (size_t)e * WROW + DDIM;
        float s = eb[e];
        #pragma unroll
        for (int i = 0; i < 16; ++i) s += tp[b][i] * wr[i];
        wsb[b * 64 + e] = s;
    }
}

// ---------------- kernel 2: MFMA logits + softmax + top2 + probs + P/f -----------
// 576 thr: waves 0..7 consumers (tg = wv&3 token group, h = wv>>2 K-half),
// wave 8 producer (stages B-frags into LDS double buffer).
__global__ __launch_bounds__(576, 1) void k2_mfma(const float* __restrict__ x,
                                                  const float* __restrict__ wsb,
                                                  const u32* __restrict__ whp,
                                                  const u32* __restrict__ wlp,
                                                  float* __restrict__ wacc,
                                                  float* __restrict__ out) {
    __shared__ __align__(16) u32  bbuf[2][4096];   // B double buffer (2 x 16 KB)
    __shared__ float lg[2][64 * 68];               // per-K-half logit partials
    __shared__ float pf[8 * 128];                  // P/f partials

    const int tid   = threadIdx.x;
    const int wv    = __builtin_amdgcn_readfirstlane(tid >> 6);
    const int lane  = tid & 63;
    const int tok0b = blockIdx.x * 64;
    const int bb    = tok0b >> 12;    // batch (uniform per block)

    if (wv == 8) {
        // ---------------- producer: B-frag DMA; vmcnt = DMAs only -----------------
        // step t needs frag-steps t (h=0) and t+32 (h=1), hi+lo: 4 x 4KB regions.
#define BDMA(t, buf) do {                                                       \
            _Pragma("unroll")                                                   \
            for (int hl = 0; hl < 2; ++hl)                                      \
            _Pragma("unroll")                                                   \
            for (int hh = 0; hh < 2; ++hh)                                      \
            _Pragma("unroll")                                                   \
            for (int g = 0; g < 4; ++g) {                                       \
                const u32* _s = (hl ? wlp : whp) +                              \
                                ((t) + hh * 32) * 1024 + g * 256 + lane * 4;    \
                u32* _d = &bbuf[buf][hl * 2048 + hh * 1024 + g * 256 + lane * 4];\
                __builtin_amdgcn_global_load_lds((gp1)_s, (lp3)_d, 16, 0, 0);   \
            }                                                                   \
        } while (0)
        BDMA(0, 0);
        asm volatile("s_waitcnt vmcnt(0)" ::: "memory");
        BAR();                                   // B(0) ready
        for (int t = 0; t < 32; ++t) {
            if (t < 31) {
                BDMA(t + 1, (t + 1) & 1);
                asm volatile("s_waitcnt vmcnt(0)" ::: "memory");
            }
            BAR();                               // B(t+1) ready / step t done
        }
#undef BDMA
    } else {
        // ---------------- consumer: vmcnt = x ring only ---------------------------
        const int tg  = wv & 3;
        const int h   = wv >> 2;
        const int row = lane & 15;    // token within 16-tile (A row)
        const int kg  = lane >> 4;    // k-group 0..3
        const int tok0 = tok0b + tg * 16;

        f32x4 acc[4];
        #pragma unroll
        for (int g = 0; g < 4; ++g) {
            const float tl = (h == 0) ? wsb[bb * 64 + g * 16 + row] : 0.0f;
            acc[g] = (f32x4){tl, tl, tl, tl};
        }
        #pragma unroll
        for (int g = 0; g < 4; ++g) asm volatile("" : "+v"(acc[g]));
        __builtin_amdgcn_sched_barrier(0);       // wsb-load wait lands before ring

        const u64 xaddr = (u64)(x + (size_t)(tok0 + row) * DDIM + h * 1024 + kg * 8);
        f32x4 xr[6][2];                          // depth-6 ring (48 VGPR)

#define XLOAD(i, T) do {                                                        \
            asm volatile("global_load_dwordx4 %0, %1, off offset:%c2"           \
                : "=&v"(xr[i][0]) : "v"(xaddr), "i"((T) * 128));                \
            asm volatile("global_load_dwordx4 %0, %1, off offset:%c2"           \
                : "=&v"(xr[i][1]) : "v"(xaddr), "i"((T) * 128 + 16));           \
        } while (0)

#define XWAIT(i) do {                                                           \
            asm volatile("s_waitcnt vmcnt(10)"                                  \
                : "+v"(xr[i][0]), "+v"(xr[i][1]));                              \
            __builtin_amdgcn_sched_barrier(0);                                  \
        } while (0)

#define MSTEP(xa, xb, BH, BL) do {                                              \
            float vv[8];                                                        \
            _Pragma("unroll")                                                   \
            for (int j = 0; j < 4; ++j) { vv[j] = (xa)[j]; vv[4 + j] = (xb)[j]; }\
            short8 Ah, Al;                                                      \
            _Pragma("unroll")                                                   \
            for (int j = 0; j < 8; ++j) {                                       \
                const float v = vv[j];                                          \
                const u16 hh = bf16rne(v);                                      \
                const u16 ll = bf16rne(v - __uint_as_float((u32)hh << 16));     \
                Ah[j] = (short)hh; Al[j] = (short)ll;                           \
            }                                                                   \
            _Pragma("unroll")                                                   \
            for (int g = 0; g < 4; ++g) {                                       \
                acc[g] = __builtin_amdgcn_mfma_f32_16x16x32_bf16(Ah, BH[g], acc[g], 0, 0, 0); \
                acc[g] = __builtin_amdgcn_mfma_f32_16x16x32_bf16(Ah, BL[g], acc[g], 0, 0, 0); \
                acc[g] = __builtin_amdgcn_mfma_f32_16x16x32_bf16(Al, BH[g], acc[g], 0, 0, 0); \
                acc[g] = __builtin_amdgcn_mfma_f32_16x16x32_bf16(Al, BL[g], acc[g], 0, 0, 0); \
            }                                                                   \
        } while (0)

        XLOAD(0, 0); XLOAD(1, 1); XLOAD(2, 2);
        XLOAD(3, 3); XLOAD(4, 4); XLOAD(5, 5);
        BAR();                                   // B(0) ready
        #pragma unroll
        for (int t = 0; t < 32; ++t) {
            short8 BH[4], BL[4];
            #pragma unroll
            for (int g = 0; g < 4; ++g) {       // B(t) from LDS (lgkm; drained by MFMA deps)
                BH[g] = *(const short8*)&bbuf[t & 1][h * 1024 + g * 256 + lane * 4];
                BL[g] = *(const short8*)&bbuf[t & 1][2048 + h * 1024 + g * 256 + lane * 4];
            }
            XWAIT(t % 6);                        // static: 10 newer x-loads outstanding
            MSTEP(xr[t % 6][0], xr[t % 6][1], BH, BL);
            XLOAD(t % 6, (t + 6) & 31);          // wrap-issue keeps vmcnt geometry exact
            BAR();                               // done reading bbuf[t&1]; B(t+1) ready
        }
        // drain dangling ring loads before VGPR reuse in epilogue
        asm volatile("s_waitcnt vmcnt(0)"
            : "+v"(xr[0][0]), "+v"(xr[0][1]), "+v"(xr[1][0]), "+v"(xr[1][1]),
              "+v"(xr[2][0]), "+v"(xr[2][1]), "+v"(xr[3][0]), "+v"(xr[3][1]),
              "+v"(xr[4][0]), "+v"(xr[4][1]), "+v"(xr[5][0]), "+v"(xr[5][1]));
        __builtin_amdgcn_sched_barrier(0);
#undef XLOAD
#undef XWAIT
#undef MSTEP

        // ---- partial-logit exchange: C col(lane&15)=expert-in-grp, row=kg*4+r ----
        #pragma unroll
        for (int g = 0; g < 4; ++g)
            #pragma unroll
            for (int r = 0; r < 4; ++r)
                lg[h][(tg * 16 + kg * 4 + r) * 68 + g * 16 + row] = acc[g][r];
    }

    __syncthreads();

    // ---- softmax/top2 for tokens wv*8 .. wv*8+7 ; lane = expert (consumers) ----
    if (wv < 8) {
        float pacc = 0.0f, facc = 0.0f;
        for (int i = 0; i < 8; ++i) {
            const int tk = wv * 8 + i;
            const float v = lg[0][tk * 68 + lane] + lg[1][tk * 68 + lane];
            float m1 = v; int i1 = lane;
            #pragma unroll
            for (int off = 32; off; off >>= 1) {
                const float ov = __shfl_xor(m1, off, 64);
                const int   oi = __shfl_xor(i1, off, 64);
                if (ov > m1 || (ov == m1 && oi < i1)) { m1 = ov; i1 = oi; }
            }
            const float vx = (lane == i1) ? -3.4e38f : v;
            float m2 = vx; int i2 = lane;
            #pragma unroll
            for (int off = 32; off; off >>= 1) {
                const float ov = __shfl_xor(m2, off, 64);
                const int   oi = __shfl_xor(i2, off, 64);
                if (ov > m2 || (ov == m2 && oi < i2)) { m2 = ov; i2 = oi; }
            }
            const float p = __expf(v - m1);
            float s = p;
            #pragma unroll
            for (int off = 32; off; off >>= 1) s += __shfl_xor(s, off, 64);
            const float rZ = 1.0f / s;
            const float pn = p * rZ;
            const int   T  = tok0b + tk;
            out[65536 + (size_t)T * 64 + lane] = pn;      // coalesced 256 B
            pacc += pn;
            facc += (lane == i1 ? 1.0f : 0.0f) + (lane == i2 ? 1.0f : 0.0f);
            if (lane == 0) {
                const float q1 = rZ, q2 = __expf(m2 - m1) * rZ;
                const float dn = 1.0f / (q1 + q2 + 1e-8f);
                float2 tw; tw.x = q1 * dn; tw.y = q2 * dn;
                *(float2*)(out + (size_t)T * 2) = tw;
                float2 ti; ti.x = (float)i1; ti.y = (float)i2;
                *(float2*)(out + 32768 + (size_t)T * 2) = ti;
            }
        }
        pf[wv * 128 + lane]      = pacc;
        pf[wv * 128 + 64 + lane] = facc;
    }
    __syncthreads();

    // ---- block-level P/f reduce -> one atomic per address per block (8 slots) ----
    if (wv == 0) {
        float ps = 0.0f, fs = 0.0f;
        #pragma unroll
        for (int w2 = 0; w2 < 8; ++w2) {
            ps += pf[w2 * 128 + lane];
            fs += pf[w2 * 128 + 64 + lane];
        }
        const int slot = blockIdx.x & 7;
        atomicAdd(wacc + slot * 128 + lane, ps);
        atomicAdd(wacc + slot * 128 + 64 + lane, fs);
    }
}

// ---------------- kernel 3: aux loss ----------------------------------------------
__global__ void k3_aux(const float* __restrict__ wsb, float* __restrict__ out) {
    const int e = threadIdx.x;  // 64 threads
    float P = 0.0f, F = 0.0f;
    #pragma unroll
    for (int s = 0; s < 8; ++s) {
        P += wsb[256 + s * 128 + e];
        F += wsb[256 + s * 128 + 64 + e];
    }
    float val = P * F;
    #pragma unroll
    for (int off = 32; off; off >>= 1) val += __shfl_xor(val, off, 64);
    if (e == 0)
        out[1114112] = 64.0f * val / (16384.0f * 2.0f * 16384.0f);
}

extern "C" void kernel_launch(void* const* d_in, const int* in_sizes, int n_in,
                              void* d_out, int out_size, void* d_ws, size_t ws_size,
                              hipStream_t stream) {
    (void)in_sizes; (void)n_in; (void)out_size; (void)ws_size;
    const float* x  = (const float*)d_in[0];
    const float* z  = (const float*)d_in[1];
    const float* Wr = (const float*)d_in[2];
    const float* Wp = (const float*)d_in[3];
    const float* bp = (const float*)d_in[4];
    const float* eb = (const float*)d_in[5];
    float* out = (float*)d_out;
    float* wsb = (float*)d_ws;
    u32*   wfH = (u32*)(wsb + 1280);          // 65536 u32 (256 KB)
    u32*   wfL = wfH + 65536;                 // 65536 u32 (256 KB)

    hipLaunchKernelGGL(k0_wsplit, dim3(256), dim3(256), 0, stream, Wr, wfH, wfL);
    hipLaunchKernelGGL(k1_task,   dim3(1),   dim3(256), 0, stream, z, Wp, bp, Wr, eb, wsb);
    hipLaunchKernelGGL(k2_mfma,   dim3(256), dim3(576), 0, stream, x, wsb,
                       wfH, wfL, wsb + 256, out);
    hipLaunchKernelGGL(k3_aux,    dim3(1),   dim3(64),  0, stream, wsb, out);
}